// Round 1
// baseline (8244.148 us; speedup 1.0000x reference)
//
#include <hip/hip_runtime.h>
#include <hip/hip_bf16.h>

#define VOCAB 8192
#define HIDDEN 1024
#define BATCH 64
#define SEQ 256

typedef __attribute__((ext_vector_type(8))) short short8;
typedef __attribute__((ext_vector_type(4))) float floatx4;

// ---------------- prep kernels ----------------

__global__ void copy_f32(const float* __restrict__ src, float* __restrict__ dst, int n) {
    int i = blockIdx.x * blockDim.x + threadIdx.x;
    if (i < n) dst[i] = src[i];
}

// w_ho (HIDDEN=1024 x VOCAB=8192, fp32 row-major) -> whoT (VOCAB x HIDDEN, bf16 row-major)
__global__ void transpose_cast(const float* __restrict__ who, __hip_bfloat16* __restrict__ whoT) {
    __shared__ float tile[32][33];
    int n0 = blockIdx.x * 32;   // along VOCAB
    int k0 = blockIdx.y * 32;   // along HIDDEN
    for (int r = threadIdx.y; r < 32; r += 8)
        tile[r][threadIdx.x] = who[(size_t)(k0 + r) * VOCAB + n0 + threadIdx.x];
    __syncthreads();
    for (int r = threadIdx.y; r < 32; r += 8)
        whoT[(size_t)(n0 + r) * HIDDEN + k0 + threadIdx.x] = __float2bfloat16(tile[threadIdx.x][r]);
}

// ---------------- recurrence step (fp32) ----------------
// h_out[b][j] = tanh( sum_k h_in[b][k]*w_hh[k][j] + w_xh[X[b][t]][j] + b_h[j] )
// grid 256 blocks x 256 thr: block = (jt in [0,64), bq in [0,4)); thread = (jl in [0,16), bl in [0,16))
__global__ __launch_bounds__(256) void rnn_step(
    const float* __restrict__ h_in, float* __restrict__ h_out,
    const float* __restrict__ w_hh, const float* __restrict__ w_xh,
    const float* __restrict__ b_h, const int* __restrict__ X,
    __hip_bfloat16* __restrict__ Hmat, int t) {
    int jt = blockIdx.x & 63;
    int bq = blockIdx.x >> 6;
    int j = jt * 16 + (threadIdx.x & 15);
    int b = bq * 16 + (threadIdx.x >> 4);
    const float* hrow = h_in + b * HIDDEN;
    float acc = 0.f;
    for (int k = 0; k < HIDDEN; k += 4) {
        float4 h4 = *(const float4*)(hrow + k);
        acc += h4.x * w_hh[(k + 0) * HIDDEN + j];
        acc += h4.y * w_hh[(k + 1) * HIDDEN + j];
        acc += h4.z * w_hh[(k + 2) * HIDDEN + j];
        acc += h4.w * w_hh[(k + 3) * HIDDEN + j];
    }
    int xrow = X[b * SEQ + t];
    acc += w_xh[(size_t)xrow * HIDDEN + j] + b_h[j];
    float hn = tanhf(acc);
    h_out[b * HIDDEN + j] = hn;
    Hmat[(size_t)(t * BATCH + b) * HIDDEN + j] = __float2bfloat16(hn);
}

// ---------------- big GEMM: C[M=16384][N=8192] = A[M][K=1024] * BT[N][K]^T + bias ----------------
#define BM 128
#define BN 128
#define BK 32
#define LDK 40  // padded K stride in bf16 elems (80B = 20 words -> 2-way bank aliasing = free)

__global__ __launch_bounds__(256) void gemm_bf16(
    const __hip_bfloat16* __restrict__ A,    // (16384,1024) row-major bf16
    const __hip_bfloat16* __restrict__ BT,   // (8192,1024) row-major bf16 (w_ho^T)
    const float* __restrict__ bias,          // b_o (8192)
    float* __restrict__ C) {
    __shared__ __align__(16) short la[BM * LDK];
    __shared__ __align__(16) short lb[BN * LDK];
    const int m0 = blockIdx.x * BM;   // gridDim.x = 128
    const int n0 = blockIdx.y * BN;   // gridDim.y = 64
    const int tid = threadIdx.x;
    const int wave = tid >> 6, lane = tid & 63;
    const int wm = (wave >> 1) * 64, wn = (wave & 1) * 64;
    const int lk = (lane >> 4) * 8;   // k offset within fragment
    const int lrow = lane & 15;       // m (resp. n) within 16-tile

    floatx4 acc[4][4] = {};

    for (int k0 = 0; k0 < HIDDEN; k0 += BK) {
        // stage A and B tiles: each is 128 rows x 32 k = 512 chunks of 16B
        for (int c = tid; c < 512; c += 256) {
            int row = c >> 2, kc = (c & 3) * 8;
            *(uint4*)&la[row * LDK + kc] = *(const uint4*)&A[(size_t)(m0 + row) * HIDDEN + k0 + kc];
            *(uint4*)&lb[row * LDK + kc] = *(const uint4*)&BT[(size_t)(n0 + row) * HIDDEN + k0 + kc];
        }
        __syncthreads();

        short8 afrag[4], bfrag[4];
        for (int i = 0; i < 4; i++) {
            afrag[i] = *(const short8*)&la[(wm + i * 16 + lrow) * LDK + lk];
            bfrag[i] = *(const short8*)&lb[(wn + i * 16 + lrow) * LDK + lk];
        }
        for (int i = 0; i < 4; i++)
            for (int jj = 0; jj < 4; jj++)
                acc[i][jj] = __builtin_amdgcn_mfma_f32_16x16x32_bf16(afrag[i], bfrag[jj], acc[i][jj], 0, 0, 0);
        __syncthreads();
    }

    // epilogue: C/D layout col=lane&15, row=(lane>>4)*4+reg
    const int col_l = lane & 15, row_q = (lane >> 4) * 4;
    for (int i = 0; i < 4; i++) {
        for (int jj = 0; jj < 4; jj++) {
            int col = n0 + wn + jj * 16 + col_l;
            float bb = bias[col];
            for (int r = 0; r < 4; r++) {
                int row = m0 + wm + i * 16 + row_q + r;
                C[(size_t)row * VOCAB + col] = acc[i][jj][r] + bb;
            }
        }
    }
}

// ---------------- launch ----------------

extern "C" void kernel_launch(void* const* d_in, const int* in_sizes, int n_in,
                              void* d_out, int out_size, void* d_ws, size_t ws_size,
                              hipStream_t stream) {
    const int*   X      = (const int*)d_in[0];
    const float* status = (const float*)d_in[1];
    const float* w_xh   = (const float*)d_in[2];
    const float* w_hh   = (const float*)d_in[3];
    const float* w_ho   = (const float*)d_in[4];
    const float* b_h    = (const float*)d_in[5];
    const float* b_o    = (const float*)d_in[6];
    float* out = (float*)d_out;

    char* ws = (char*)d_ws;
    float* hA = (float*)ws;                                   // 256 KB
    float* hB = (float*)(ws + 262144);                        // 256 KB
    __hip_bfloat16* Hm   = (__hip_bfloat16*)(ws + 524288);    // 32 MB (16384x1024 bf16)
    __hip_bfloat16* whoT = (__hip_bfloat16*)(ws + 524288 + 33554432);  // 16 MB

    // h0 = status
    copy_f32<<<256, 256, 0, stream>>>(status, hA, BATCH * HIDDEN);
    // w_ho -> bf16 transposed
    transpose_cast<<<dim3(VOCAB / 32, HIDDEN / 32), dim3(32, 8), 0, stream>>>(w_ho, whoT);

    // sequential recurrence; ping-pong h buffers
    for (int t = 0; t < SEQ; t++) {
        const float* hi = (t & 1) ? hB : hA;
        float*       ho = (t & 1) ? hA : hB;
        rnn_step<<<256, 256, 0, stream>>>(hi, ho, w_hh, w_xh, b_h, X, Hm, t);
    }

    // Y = H @ w_ho + b_o  (M=16384, N=8192, K=1024), written straight into d_out
    gemm_bf16<<<dim3(SEQ * BATCH / BM, VOCAB / BN), 256, 0, stream>>>(Hm, whoT, b_o, out);

    // h_final: t=255 (odd) wrote hA
    copy_f32<<<256, 256, 0, stream>>>(hA, out + (size_t)SEQ * BATCH * VOCAB, BATCH * HIDDEN);
}

// Round 2
// 3073.364 us; speedup vs baseline: 2.6825x; 2.6825x over previous
//
#include <hip/hip_runtime.h>
#include <hip/hip_bf16.h>
#include <stdint.h>

#define VOCAB 8192
#define HIDDEN 1024
#define BATCH 64
#define SEQ 256

typedef __attribute__((ext_vector_type(8))) short short8;
typedef __attribute__((ext_vector_type(4))) float floatx4;

__device__ __forceinline__ short f2bf(float x) {
    __hip_bfloat16 h = __float2bfloat16(x);
    return *reinterpret_cast<short*>(&h);
}

// async global->LDS, 16B per lane. LDS dest must equal (wave-uniform base + lane*16).
__device__ __forceinline__ void load_lds16(const void* g, void* l) {
    __builtin_amdgcn_global_load_lds(
        (const __attribute__((address_space(1))) void*)(uintptr_t)g,
        (__attribute__((address_space(3))) void*)(uint32_t)(uintptr_t)l,
        16, 0, 0);
}

// ---------------- prep kernels ----------------

// status fp32 -> Hall[0] bf16
__global__ void cast_h0(const float* __restrict__ s, short* __restrict__ d) {
    int i = blockIdx.x * 256 + threadIdx.x;
    d[i] = f2bf(s[i]);
}

// w_ho (1024 x 8192 fp32 row-major) -> whoT (8192 x 1024 bf16 row-major)
__global__ void transpose_cast(const float* __restrict__ who, short* __restrict__ whoT) {
    __shared__ float tile[32][33];
    int n0 = blockIdx.x * 32;   // along VOCAB
    int k0 = blockIdx.y * 32;   // along HIDDEN
    for (int r = threadIdx.y; r < 32; r += 8)
        tile[r][threadIdx.x] = who[(size_t)(k0 + r) * VOCAB + n0 + threadIdx.x];
    __syncthreads();
    for (int r = threadIdx.y; r < 32; r += 8)
        whoT[(size_t)(n0 + r) * HIDDEN + k0 + threadIdx.x] = f2bf(tile[threadIdx.x][r]);
}

// ---------------- persistent recurrence ----------------
// 64 wgs x 256 thr. wg g owns h columns [16g, 16g+16). w_hh slice lives in LDS
// (B-operand layout [n][k], stride 1032 => 2-way bank aliasing = free).
// Per step: wave w computes rows [16w,16w+16) x 16 cols via 32 MFMAs; A-frags
// read directly from global Hall[t] (16 fully-used 64B lines per load, L2/L3-hot).
// Steps separated by device-scope grid barrier (cross-XCD visibility, G16).
__global__ __launch_bounds__(256) void rnn_recur(
    short* __restrict__ Hall,              // (SEQ+1, 64, 1024) bf16
    const float* __restrict__ w_hh, const float* __restrict__ w_xh,
    const float* __restrict__ b_h, const int* __restrict__ X,
    float* __restrict__ hfin, int* bar) {
    __shared__ short Bs[16 * 1032];
    const int g = blockIdx.x;
    const int tid = threadIdx.x;
    const int w = tid >> 6, lane = tid & 63;
    const int q = lane >> 4, r15 = lane & 15;

    // stage w_hh slice once: Bs[c][k] = bf16(w_hh[k][16g+c])
    for (int idx = tid; idx < 16 * 1024; idx += 256) {
        int c = idx & 15, k = idx >> 4;
        Bs[c * 1032 + k] = f2bf(w_hh[(size_t)k * HIDDEN + g * 16 + c]);
    }
    __syncthreads();

    const int jcol = g * 16 + r15;
    const float bh = b_h[jcol];
    int brow[4];
#pragma unroll
    for (int r = 0; r < 4; r++) brow[r] = w * 16 + q * 4 + r;
    const int afr_off = (w * 16 + r15) * HIDDEN + q * 8;  // A-fragment row offset

    for (int t = 0; t < SEQ; t++) {
        // x gather: issue early, consumed at epilogue (hidden under MFMA loop)
        int xrow[4];
#pragma unroll
        for (int r = 0; r < 4; r++) xrow[r] = X[brow[r] * SEQ + t];
        float xe[4];
#pragma unroll
        for (int r = 0; r < 4; r++) xe[r] = w_xh[(size_t)xrow[r] * HIDDEN + jcol];

        const short* Ab = Hall + (size_t)t * (BATCH * HIDDEN) + afr_off;
        floatx4 a0 = {0.f, 0.f, 0.f, 0.f}, a1 = a0, a2 = a0, a3 = a0;
#pragma unroll
        for (int k0 = 0; k0 < HIDDEN; k0 += 128) {
            short8 f0 = *(const short8*)(Ab + k0);
            short8 f1 = *(const short8*)(Ab + k0 + 32);
            short8 f2 = *(const short8*)(Ab + k0 + 64);
            short8 f3 = *(const short8*)(Ab + k0 + 96);
            const short* Bb = &Bs[r15 * 1032 + k0 + q * 8];
            short8 b0 = *(const short8*)(Bb);
            short8 b1 = *(const short8*)(Bb + 32);
            short8 b2 = *(const short8*)(Bb + 64);
            short8 b3 = *(const short8*)(Bb + 96);
            a0 = __builtin_amdgcn_mfma_f32_16x16x32_bf16(f0, b0, a0, 0, 0, 0);
            a1 = __builtin_amdgcn_mfma_f32_16x16x32_bf16(f1, b1, a1, 0, 0, 0);
            a2 = __builtin_amdgcn_mfma_f32_16x16x32_bf16(f2, b2, a2, 0, 0, 0);
            a3 = __builtin_amdgcn_mfma_f32_16x16x32_bf16(f3, b3, a3, 0, 0, 0);
        }
        floatx4 acc = (a0 + a1) + (a2 + a3);

        short* Hnext = Hall + (size_t)(t + 1) * (BATCH * HIDDEN);
#pragma unroll
        for (int r = 0; r < 4; r++) {
            float v = acc[r] + xe[r] + bh;
            float h = tanhf(v);
            Hnext[brow[r] * HIDDEN + jcol] = f2bf(h);
            if (t == SEQ - 1) hfin[brow[r] * HIDDEN + jcol] = h;
        }

        // grid barrier: release -> count -> poll -> acquire
        __syncthreads();
        if (tid == 0) {
            __builtin_amdgcn_fence(__ATOMIC_RELEASE, "agent");
            __hip_atomic_fetch_add(bar, 1, __ATOMIC_RELAXED, __HIP_MEMORY_SCOPE_AGENT);
            const int target = 64 * (t + 1);
            while (__hip_atomic_load(bar, __ATOMIC_RELAXED, __HIP_MEMORY_SCOPE_AGENT) < target)
                __builtin_amdgcn_s_sleep(1);
            __builtin_amdgcn_fence(__ATOMIC_ACQUIRE, "agent");
        }
        __syncthreads();
    }
}

// ---------------- big GEMM (m97 structure): C[16384][8192] = A[16384][1024] * BT[8192][1024]^T + bias
#define GBM 128
#define GBN 128
#define GBK 32

__global__ __launch_bounds__(256) void gemm_bf16(
    const short* __restrict__ A, const short* __restrict__ BT,
    const float* __restrict__ bias, float* __restrict__ C) {
    __shared__ __align__(16) short la[GBM * GBK];
    __shared__ __align__(16) short lb[GBN * GBK];
    const int m0 = blockIdx.x * GBM;
    const int n0 = blockIdx.y * GBN;
    const int tid = threadIdx.x;
    const int wave = tid >> 6, lane = tid & 63;
    const int wm = (wave >> 1) * 64, wn = (wave & 1) * 64;
    const int q = lane >> 4, r15 = lane & 15;

    floatx4 acc[4][4] = {};

    for (int k0 = 0; k0 < HIDDEN; k0 += GBK) {
        // stage 128x32 A and B tiles via global_load_lds; XOR-swizzle the global
        // k-chunk so slot (row,s) holds chunk s^((row>>1)&3) -> 2-way LDS banks.
#pragma unroll
        for (int i = 0; i < 2; i++) {
            int c = wave * 128 + i * 64 + lane;       // LDS dest = base + lane*16
            int row = c >> 2, s = c & 3;
            int gq = s ^ ((row >> 1) & 3);
            load_lds16(&A[(size_t)(m0 + row) * HIDDEN + k0 + gq * 8], &la[c * 8]);
            load_lds16(&BT[(size_t)(n0 + row) * HIDDEN + k0 + gq * 8], &lb[c * 8]);
        }
        __syncthreads();

        short8 af[4], bf[4];
#pragma unroll
        for (int i = 0; i < 4; i++) {
            int ra = wm + i * 16 + r15;
            af[i] = *(const short8*)&la[ra * GBK + (q ^ ((ra >> 1) & 3)) * 8];
            int rb = wn + i * 16 + r15;
            bf[i] = *(const short8*)&lb[rb * GBK + (q ^ ((rb >> 1) & 3)) * 8];
        }
#pragma unroll
        for (int i = 0; i < 4; i++)
#pragma unroll
            for (int jj = 0; jj < 4; jj++)
                acc[i][jj] = __builtin_amdgcn_mfma_f32_16x16x32_bf16(af[i], bf[jj], acc[i][jj], 0, 0, 0);
        __syncthreads();
    }

    const int col_l = lane & 15, row_q = (lane >> 4) * 4;
#pragma unroll
    for (int i = 0; i < 4; i++) {
#pragma unroll
        for (int jj = 0; jj < 4; jj++) {
            int col = n0 + wn + jj * 16 + col_l;
            float bb = bias[col];
#pragma unroll
            for (int r = 0; r < 4; r++) {
                int row = m0 + wm + i * 16 + row_q + r;
                C[(size_t)row * VOCAB + col] = acc[i][jj][r] + bb;
            }
        }
    }
}

// ---------------- launch ----------------

extern "C" void kernel_launch(void* const* d_in, const int* in_sizes, int n_in,
                              void* d_out, int out_size, void* d_ws, size_t ws_size,
                              hipStream_t stream) {
    const int*   X      = (const int*)d_in[0];
    const float* status = (const float*)d_in[1];
    const float* w_xh   = (const float*)d_in[2];
    const float* w_hh   = (const float*)d_in[3];
    const float* w_ho   = (const float*)d_in[4];
    const float* b_h    = (const float*)d_in[5];
    const float* b_o    = (const float*)d_in[6];
    float* out = (float*)d_out;

    char* ws = (char*)d_ws;
    int*   bar  = (int*)ws;                                    // 4 KB slot
    short* Hall = (short*)(ws + 4096);                         // (257,64,1024) bf16 = 33.7 MB
    short* whoT = (short*)(ws + 4096 + (size_t)(SEQ + 1) * BATCH * HIDDEN * 2);  // 16 MB

    hipMemsetAsync(bar, 0, 4, stream);
    cast_h0<<<BATCH * HIDDEN / 256, 256, 0, stream>>>(status, Hall);
    transpose_cast<<<dim3(VOCAB / 32, HIDDEN / 32), dim3(32, 8), 0, stream>>>(w_ho, whoT);

    rnn_recur<<<64, 256, 0, stream>>>(Hall, w_hh, w_xh, b_h, X,
                                      out + (size_t)SEQ * BATCH * VOCAB, bar);

    // Y[t] = Hall[t+1] @ w_ho + b_o
    gemm_bf16<<<dim3(SEQ * BATCH / GBM, VOCAB / GBN), 256, 0, stream>>>(
        Hall + BATCH * HIDDEN, whoT, b_o, out);
}